// Round 18
// baseline (240.987 us; speedup 1.0000x reference)
//
#include <hip/hip_runtime.h>
#include <cmath>

// Problem constants (from reference)
#define NB 4
#define NP 8192            // 2^13 points per batch
#define NE 262144          // 2^18 edges per batch
#define NCIN 32
#define NCOUT 32
#define NH 16
#define GAMMA 4.0f
#define NFEAT (NB * NP * NCIN)      // 1,048,576 floats (4 MB)
#define TILES_PER_BATCH (NE / 64)

// Src-binning geometry (R11/R15-proven)
#define NSLAB 512                   // bin blocks; slab = 2048 contiguous edges
#define SLAB  2048
#define SREG  8                     // src regions per batch (1024 points each)
#define RPTS  1024                  // points per src region (64 KB f16 in LDS)
#define CAP   384                   // records per (slab, region); mean 256, +8 sigma
#define OVCAP 8192                  // overflow list capacity

typedef _Float16 half8 __attribute__((ext_vector_type(8)));
typedef float floatx4 __attribute__((ext_vector_type(4)));

// ---------------------------------------------------------------------------
// Bin pass (R17): records buffered in LDS, segments flushed contiguously.
// ---------------------------------------------------------------------------
__global__ __launch_bounds__(256)
void bin_kernel(const float* __restrict__ edge_vec,
                const int* __restrict__ edge_src,
                const int* __restrict__ edge_dst,
                uint2* __restrict__ rec,
                int* __restrict__ scnt,
                int* __restrict__ ovfcnt,
                uint4* __restrict__ ovfrec)
{
    __shared__ uint2 buf[SREG][CAP];                    // 24 KiB record buffer
    __shared__ int lcnt[SREG];
    const int tid = threadIdx.x;
    if (tid < SREG) lcnt[tid] = 0;
    __syncthreads();

    const long e0 = (long)blockIdx.x * SLAB;
    const int batch = (int)(e0 >> 18);
    const long segbase = (long)blockIdx.x * SREG;

    #pragma unroll 1
    for (int k = 0; k < SLAB / 256; ++k) {
        const long e = e0 + k * 256 + tid;              // coalesced
        const float* ev = edge_vec + e * 3;
        const float vx = ev[0], vy = ev[1], vz = ev[2];
        // self-interaction zeroing in ref is a numeric no-op (r<1e-10 -> r=0)
        const float r = sqrtf(vx * vx + vy * vy + vz * vz);
        const int src = edge_src[e];
        const int dst = edge_dst[e];
        const int rg  = src >> 10;                      // src region 0..7
        const int pos = atomicAdd(&lcnt[rg], 1);        // LDS atomic
        if (pos < CAP) {
            uint2 rc;
            rc.x = __float_as_uint(r);
            rc.y = (unsigned)(src & 1023) | ((unsigned)dst << 10);
            buf[rg][pos] = rc;                          // LDS write, no fabric
        } else {
            const int op = atomicAdd(ovfcnt, 1);        // ~never taken
            if (op < OVCAP) {
                uint4 rc;
                rc.x = __float_as_uint(r);
                rc.y = (unsigned)src;
                rc.z = (unsigned)dst;
                rc.w = (unsigned)batch;
                ovfrec[op] = rc;
            }
        }
    }
    __syncthreads();

    #pragma unroll 1
    for (int rg = 0; rg < SREG; ++rg) {
        const int c = min(lcnt[rg], CAP);
        uint2* dstp = rec + (segbase + rg) * CAP;
        for (int i = tid; i < c; i += 256)
            dstp[i] = buf[rg][i];
    }
    if (tid < SREG) scnt[segbase + tid] = min(lcnt[tid], CAP);
}

// ---------------------------------------------------------------------------
// Main kernel (R15 geometry) with 2-CHUNK JAMMING.
//
// Cycle audit of R15's 135 us: 324K cyc/CU / (8 waves x 32 chunks) = ~1270
// cyc per 16-edge chunk. The chunk body = 32 ds_read_b128 + 32 MFMAs in TWO
// dependent accumulator chains (16 links x ~36 cyc dep latency) — with only
// 2 waves/SIMD (LDS-limited 1 block/CU) nothing hides the chain stalls.
// Fix: process 32 edges (2 sub-chunks A,B) per iteration. Per K-step s:
// read b0,b1 ONCE, issue 4 MFMAs (A/B x Lo/Hi) -> 4 independent chains
// (2x the ILP) and HALF the wsw LDS reads per edge. Extra ~50 VGPRs are
// free: occupancy is LDS-limited, 8 waves allows up to 256 VGPR.
//
// GEMM view: msg[e, o] = sum_k Z[e,k] * W2T[k,o],  k = h*32 + i, K = 512
//   Z[e, h*32+i] = rbf_h(e) * x_src[e][i]
// MFMA f32_16x16x32_f16 layouts (HW-verified, learn_hip m89/m91):
//   A: lane holds A[m=lane&15][k_local=(lane>>4)*8+j], j=0..7
//   B: lane holds B[k_local][n=lane&15]
//   D: lane holds D[row=(lane>>4)*4+rr][col=m]
// Masked tail rows: r=1e9 -> rbf=0 -> D-row=0 -> atomicAdd of 0 (harmless).
// ---------------------------------------------------------------------------
__global__ __launch_bounds__(512, 2)
void pconv_src_kernel(const float* __restrict__ features,
                      const float* __restrict__ W,
                      const float* __restrict__ mu,
                      const int* __restrict__ n_norm_p,
                      const uint2* __restrict__ rec,
                      const int* __restrict__ scnt,
                      float* __restrict__ out)
{
    __shared__ _Float16 wsw[16 * 2 * 64 * 8];      // 32 KiB, B-fragment order
    __shared__ _Float16 flds[RPTS * NCIN];         // 64 KiB region features
    __shared__ uint2    recs[8][CAP];              // 24 KiB per-wave records
    __shared__ float mus[16];

    const int tid = threadIdx.x;                   // 0..511
    for (int idx = tid; idx < 16384; idx += 512) {
        int j = idx & 7;
        int l = (idx >> 3) & 63;
        int u = (idx >> 9) & 1;
        int s = idx >> 10;
        int n = (l & 15) + (u << 4);               // output channel o
        int i = ((l >> 4) << 3) | j;               // input channel
        wsw[idx] = (_Float16)W[(s * NCOUT + n) * NCIN + i];
    }
    if (tid < 16) mus[tid] = mu[tid];

    const int bin   = blockIdx.x >> 3;             // 0..31 = batch*8 + region
    const int sub   = blockIdx.x & 7;
    const int batch = bin >> 3;
    const int reg   = bin & 7;

    // stage this region's features: f32 global -> f16 LDS (128 KB read)
    const float* fb = features + ((long)batch * NP + (long)reg * RPTS) * NCIN;
    for (int j = tid; j < RPTS * NCIN / 8; j += 512) {
        const floatx4* s = (const floatx4*)fb + (long)j * 2;
        floatx4 v0 = s[0], v1 = s[1];
        half8 h;
        h[0] = (_Float16)v0[0]; h[1] = (_Float16)v0[1];
        h[2] = (_Float16)v0[2]; h[3] = (_Float16)v0[3];
        h[4] = (_Float16)v1[0]; h[5] = (_Float16)v1[1];
        h[6] = (_Float16)v1[2]; h[7] = (_Float16)v1[3];
        *((half8*)flds + j) = h;
    }
    __syncthreads();

    const int lane = tid & 63;
    const int wv   = tid >> 6;                     // 0..7
    const int m    = lane & 15;                    // edge row / channel col
    const int q    = lane >> 4;

    const int nn = n_norm_p[0];
    const float scale = (nn > 0) ? rsqrtf((float)nn) : 1.0f;
    float* obase = out + ((long)batch * NP) * NCOUT;

    #pragma unroll 1
    for (int sl = 0; sl < 2; ++sl) {
        // this wave's slab: 16 slabs per sub, 2 per wave
        const int slab = batch * 128 + sub * 16 + wv * 2 + sl;
        const long segi = (long)slab * SREG + reg;
        const int cnt = scnt[segi];
        const uint2* rb = rec + segi * CAP;
        if (cnt <= 0) continue;

        // ---- stage the whole segment into this wave's LDS area
        for (int i = lane; i < cnt; i += 64)
            recs[wv][i] = rb[i];

        #pragma unroll 1
        for (int c0 = 0; c0 < cnt; c0 += 32) {
            const bool actA = (c0 + m)      < cnt;
            const bool actB = (c0 + 16 + m) < cnt;
            const uint2 rcA = recs[wv][actA ? (c0 + m)      : 0];
            const uint2 rcB = recs[wv][actB ? (c0 + 16 + m) : 0];
            const float rA = actA ? __uint_as_float(rcA.x) : 1e9f;
            const float rB = actB ? __uint_as_float(rcB.x) : 1e9f;

            // gathers from LDS (no fabric traffic)
            half8 xhA = *(const half8*)(flds + (int)(rcA.y & 1023u) * NCIN + q * 8);
            half8 xhB = *(const half8*)(flds + (int)(rcB.y & 1023u) * NCIN + q * 8);

            float rbfA[16], rbfB[16];
            #pragma unroll
            for (int s = 0; s < 16; ++s) {
                float dA = rA - mus[s];
                float dB = rB - mus[s];
                rbfA[s] = __expf(-GAMMA * dA * dA);   // masked -> 0
                rbfB[s] = __expf(-GAMMA * dB * dB);
            }

            floatx4 aLoA = {0.f,0.f,0.f,0.f}, aHiA = {0.f,0.f,0.f,0.f};
            floatx4 aLoB = {0.f,0.f,0.f,0.f}, aHiB = {0.f,0.f,0.f,0.f};

            #pragma unroll
            for (int s = 0; s < 16; ++s) {
                const _Float16 rhA = (_Float16)rbfA[s];
                const _Float16 rhB = (_Float16)rbfB[s];
                half8 aA = xhA * rhA;                 // 4x v_pk_mul_f16
                half8 aB = xhB * rhB;
                half8 b0 = *(const half8*)(wsw + ((s * 2 + 0) * 64 + lane) * 8);
                half8 b1 = *(const half8*)(wsw + ((s * 2 + 1) * 64 + lane) * 8);
                // 4 INDEPENDENT accumulator chains, shared b0/b1 reads
                aLoA = __builtin_amdgcn_mfma_f32_16x16x32_f16(aA, b0, aLoA, 0, 0, 0);
                aLoB = __builtin_amdgcn_mfma_f32_16x16x32_f16(aB, b0, aLoB, 0, 0, 0);
                aHiA = __builtin_amdgcn_mfma_f32_16x16x32_f16(aA, b1, aHiA, 0, 0, 0);
                aHiB = __builtin_amdgcn_mfma_f32_16x16x32_f16(aB, b1, aHiB, 0, 0, 0);
            }

            // Epilogues: D[row=q*4+rr][col=m]; 16 lanes cover 16 consecutive
            // channels -> coalesced 64 B atomic segments, fire-and-forget.
            #pragma unroll
            for (int rr = 0; rr < 4; ++rr) {
                const unsigned yA = (unsigned)__shfl((int)rcA.y, (q << 2) + rr, 64);
                const int dstA = (int)((yA >> 10) & 8191u);
                float* orowA = obase + (long)dstA * NCOUT;
                atomicAdd(orowA + m,      aLoA[rr] * scale);
                atomicAdd(orowA + m + 16, aHiA[rr] * scale);
            }
            #pragma unroll
            for (int rr = 0; rr < 4; ++rr) {
                const unsigned yB = (unsigned)__shfl((int)rcB.y, (q << 2) + rr, 64);
                const int dstB = (int)((yB >> 10) & 8191u);
                float* orowB = obase + (long)dstB * NCOUT;
                atomicAdd(orowB + m,      aLoB[rr] * scale);
                atomicAdd(orowB + m + 16, aHiB[rr] * scale);
            }
        }
    }
}

// ---------------------------------------------------------------------------
// Overflow cleanup: scalar per-edge compute for CAP-spilled records
// (expected count: 0). f32 math, atomic scatter.
// ---------------------------------------------------------------------------
__global__ __launch_bounds__(256)
void ovf_kernel(const float* __restrict__ features,
                const float* __restrict__ W,
                const float* __restrict__ mu,
                const int* __restrict__ n_norm_p,
                const int* __restrict__ ovfcnt,
                const uint4* __restrict__ ovfrec,
                float* __restrict__ out)
{
    const int n = min(ovfcnt[0], OVCAP);
    if (n == 0) return;
    const int nn = n_norm_p[0];
    const float scale = (nn > 0) ? rsqrtf((float)nn) : 1.0f;

    for (int idx = blockIdx.x * blockDim.x + threadIdx.x; idx < n * NCOUT;
         idx += gridDim.x * blockDim.x) {
        const int e = idx >> 5, o = idx & 31;
        const uint4 rc = ovfrec[e];
        const float r = __uint_as_float(rc.x);
        const int src = (int)rc.y, dst = (int)rc.z, b = (int)rc.w;
        const float* x = features + ((long)b * NP + src) * NCIN;
        float acc = 0.f;
        for (int h = 0; h < NH; ++h) {
            float d = r - mu[h];
            float rb = __expf(-GAMMA * d * d);
            float s = 0.f;
            for (int i = 0; i < NCIN; ++i)
                s += W[(h * NCOUT + o) * NCIN + i] * x[i];
            acc += rb * s;
        }
        atomicAdd(out + ((long)b * NP + dst) * NCOUT + o, acc * scale);
    }
}

// ---------------------------------------------------------------------------
// Fallback A (ws >= 2 MB): round-5 pipeline verbatim (248 us).
// ---------------------------------------------------------------------------
__global__ __launch_bounds__(256)
void cvt_f16_kernel(const float* __restrict__ features, _Float16* __restrict__ f16t)
{
    const int i = blockIdx.x * blockDim.x + threadIdx.x;    // 0 .. 131071
    const floatx4* src = (const floatx4*)features + (long)i * 2;
    floatx4 v0 = src[0], v1 = src[1];
    half8 h;
    h[0] = (_Float16)v0[0]; h[1] = (_Float16)v0[1];
    h[2] = (_Float16)v0[2]; h[3] = (_Float16)v0[3];
    h[4] = (_Float16)v1[0]; h[5] = (_Float16)v1[1];
    h[6] = (_Float16)v1[2]; h[7] = (_Float16)v1[3];
    *((half8*)f16t + i) = h;
}

__global__ __launch_bounds__(256, 4)
void pconv_f16_kernel(const _Float16* __restrict__ feat16,
                      const float* __restrict__ edge_vec,
                      const float* __restrict__ W,
                      const float* __restrict__ mu,
                      const int* __restrict__ edge_src,
                      const int* __restrict__ edge_dst,
                      const int* __restrict__ n_norm_p,
                      float* __restrict__ out)
{
    __shared__ _Float16 wsw[16 * 2 * 64 * 8];
    __shared__ float mus[16];

    const int tid = threadIdx.x;
    for (int idx = tid; idx < 16384; idx += 256) {
        int j = idx & 7;
        int l = (idx >> 3) & 63;
        int u = (idx >> 9) & 1;
        int s = idx >> 10;
        int n = (l & 15) + (u << 4);
        int i = ((l >> 4) << 3) | j;
        wsw[idx] = (_Float16)W[(s * NCOUT + n) * NCIN + i];
    }
    if (tid < 16) mus[tid] = mu[tid];
    __syncthreads();

    const int lane = tid & 63;
    const int wv   = tid >> 6;
    const int m    = lane & 15;
    const int q    = lane >> 4;

    const int nn = n_norm_p[0];
    const float scale = (nn > 0) ? rsqrtf((float)nn) : 1.0f;

    const int g    = blockIdx.x & 7;
    const int bb   = g >> 1;
    const int sub  = g & 1;
    const int bi   = blockIdx.x >> 3;

    const _Float16* fbase = feat16 + ((long)bb << 13) * NCIN;
    float* obase = out + ((long)bb << 13) * NCOUT;
    const long ebatch = (long)bb * NE;

    for (int i = bi; i < TILES_PER_BATCH / 2; i += 128) {
        const int  tloc  = (i << 1) + sub;
        const long ebase = ebatch + (long)tloc * 64 + (long)wv * 16;
        const long ge    = ebase + m;
        const int  src   = __builtin_nontemporal_load(edge_src + ge);

        half8 xh = *(const half8*)(fbase + (long)src * NCIN + q * 8);

        const float* ev = edge_vec + ge * 3;
        float vx = __builtin_nontemporal_load(ev + 0);
        float vy = __builtin_nontemporal_load(ev + 1);
        float vz = __builtin_nontemporal_load(ev + 2);
        float r = sqrtf(vx * vx + vy * vy + vz * vz);

        float rbf[16];
        #pragma unroll
        for (int s = 0; s < 16; ++s) {
            float d = r - mus[s];
            rbf[s] = __expf(-GAMMA * d * d);
        }

        floatx4 accLo = {0.f, 0.f, 0.f, 0.f};
        floatx4 accHi = {0.f, 0.f, 0.f, 0.f};

        #pragma unroll
        for (int s = 0; s < 16; ++s) {
            const _Float16 rh = (_Float16)rbf[s];
            half8 a = xh * rh;
            half8 b0 = *(const half8*)(wsw + ((s * 2 + 0) * 64 + lane) * 8);
            half8 b1 = *(const half8*)(wsw + ((s * 2 + 1) * 64 + lane) * 8);
            accLo = __builtin_amdgcn_mfma_f32_16x16x32_f16(a, b0, accLo, 0, 0, 0);
            accHi = __builtin_amdgcn_mfma_f32_16x16x32_f16(a, b1, accHi, 0, 0, 0);
        }

        #pragma unroll
        for (int rr = 0; rr < 4; ++rr) {
            const long e2  = ebase + q * 4 + rr;
            const int  dst = __builtin_nontemporal_load(edge_dst + e2);
            float* orow = obase + (long)dst * NCOUT;
            atomicAdd(orow + m,      accLo[rr] * scale);
            atomicAdd(orow + m + 16, accHi[rr] * scale);
        }
    }
}

// ---------------------------------------------------------------------------
// Fallback B (no workspace): round-3 kernel (f32 gathers).
// ---------------------------------------------------------------------------
__global__ __launch_bounds__(256, 4)
void pconv_mfma_kernel(const float* __restrict__ features,
                       const float* __restrict__ edge_vec,
                       const float* __restrict__ W,
                       const float* __restrict__ mu,
                       const int* __restrict__ edge_src,
                       const int* __restrict__ edge_dst,
                       const int* __restrict__ n_norm_p,
                       float* __restrict__ out)
{
    __shared__ _Float16 wsw[16 * 2 * 64 * 8];
    __shared__ float mus[16];

    const int tid = threadIdx.x;
    for (int idx = tid; idx < 16384; idx += 256) {
        int j = idx & 7;
        int l = (idx >> 3) & 63;
        int u = (idx >> 9) & 1;
        int s = idx >> 10;
        int n = (l & 15) + (u << 4);
        int i = ((l >> 4) << 3) | j;
        wsw[idx] = (_Float16)W[(s * NCOUT + n) * NCIN + i];
    }
    if (tid < 16) mus[tid] = mu[tid];
    __syncthreads();

    const int lane = tid & 63;
    const int wv   = tid >> 6;
    const int m    = lane & 15;
    const int q    = lane >> 4;

    const int nn = n_norm_p[0];
    const float scale = (nn > 0) ? rsqrtf((float)nn) : 1.0f;

    const int g    = blockIdx.x & 7;
    const int bb   = g >> 1;
    const int sub  = g & 1;
    const int bi   = blockIdx.x >> 3;

    const float* fbase = features + ((long)bb << 13) * NCIN;
    float* obase = out + ((long)bb << 13) * NCOUT;
    const long ebatch = (long)bb * NE;

    for (int i = bi; i < TILES_PER_BATCH / 2; i += 128) {
        const int  tloc  = (i << 1) + sub;
        const long ebase = ebatch + (long)tloc * 64 + (long)wv * 16;
        const long ge    = ebase + m;
        const int  src   = edge_src[ge];

        const float* xrow = fbase + (long)src * NCIN + q * 8;
        floatx4 xa = *(const floatx4*)(xrow);
        floatx4 xb = *(const floatx4*)(xrow + 4);

        const float* ev = edge_vec + ge * 3;
        float vx = ev[0], vy = ev[1], vz = ev[2];
        float r = sqrtf(vx * vx + vy * vy + vz * vz);

        float rbf[16];
        #pragma unroll
        for (int s = 0; s < 16; ++s) {
            float d = r - mus[s];
            rbf[s] = __expf(-GAMMA * d * d);
        }

        floatx4 accLo = {0.f, 0.f, 0.f, 0.f};
        floatx4 accHi = {0.f, 0.f, 0.f, 0.f};

        #pragma unroll
        for (int s = 0; s < 16; ++s) {
            const float rb = rbf[s];
            half8 a;
            a[0] = (_Float16)(rb * xa[0]);
            a[1] = (_Float16)(rb * xa[1]);
            a[2] = (_Float16)(rb * xa[2]);
            a[3] = (_Float16)(rb * xa[3]);
            a[4] = (_Float16)(rb * xb[0]);
            a[5] = (_Float16)(rb * xb[1]);
            a[6] = (_Float16)(rb * xb[2]);
            a[7] = (_Float16)(rb * xb[3]);
            half8 b0 = *(const half8*)(wsw + ((s * 2 + 0) * 64 + lane) * 8);
            half8 b1 = *(const half8*)(wsw + ((s * 2 + 1) * 64 + lane) * 8);
            accLo = __builtin_amdgcn_mfma_f32_16x16x32_f16(a, b0, accLo, 0, 0, 0);
            accHi = __builtin_amdgcn_mfma_f32_16x16x32_f16(a, b1, accHi, 0, 0, 0);
        }

        #pragma unroll
        for (int rr = 0; rr < 4; ++rr) {
            const long e2  = ebase + q * 4 + rr;
            const int  dst = edge_dst[e2];
            float* orow = obase + (long)dst * NCOUT;
            atomicAdd(orow + m,      accLo[rr] * scale);
            atomicAdd(orow + m + 16, accHi[rr] * scale);
        }
    }
}

extern "C" void kernel_launch(void* const* d_in, const int* in_sizes, int n_in,
                              void* d_out, int out_size, void* d_ws, size_t ws_size,
                              hipStream_t stream) {
    const float* features = (const float*)d_in[0];
    const float* edge_vec = (const float*)d_in[1];
    const float* W        = (const float*)d_in[2];
    const float* mu       = (const float*)d_in[3];
    const int*   edge_src = (const int*)d_in[4];
    const int*   edge_dst = (const int*)d_in[5];
    const int*   n_norm   = (const int*)d_in[6];
    float* out = (float*)d_out;

    // harness poisons d_out; all paths accumulate via atomics
    hipMemsetAsync(out, 0, (size_t)out_size * sizeof(float), stream);

    // ws layout: rec[512*8*CAP] (8 B) | scnt[4096] | ovfcnt | ovfrec[8192*16B]
    const size_t rec_bytes = (size_t)NSLAB * SREG * CAP * sizeof(uint2); // 12.6 MB
    const size_t cnt_bytes = (size_t)NSLAB * SREG * sizeof(int);         // 16 KB
    const size_t ovc_bytes = 64;
    const size_t ovr_bytes = (size_t)OVCAP * sizeof(uint4);              // 128 KB
    const size_t need_full = rec_bytes + cnt_bytes + ovc_bytes + ovr_bytes;
    const size_t f16_bytes = (size_t)NFEAT * sizeof(_Float16);           // 2 MB

    if (d_ws != nullptr && ws_size >= need_full) {
        char* ws = (char*)d_ws;
        uint2* rec    = (uint2*)ws;
        int*   scnt   = (int*)(ws + rec_bytes);
        int*   ovfcnt = (int*)(ws + rec_bytes + cnt_bytes);
        uint4* ovfrec = (uint4*)(ws + rec_bytes + cnt_bytes + ovc_bytes);

        hipMemsetAsync(ovfcnt, 0, sizeof(int), stream);
        bin_kernel<<<NSLAB, 256, 0, stream>>>(edge_vec, edge_src, edge_dst,
                                              rec, scnt, ovfcnt, ovfrec);
        // grid 256 = NB * SREG * 8 = 4*8*8 -> exactly 1 block/CU
        pconv_src_kernel<<<NB * SREG * 8, 512, 0, stream>>>(
            features, W, mu, n_norm, rec, scnt, out);
        ovf_kernel<<<64, 256, 0, stream>>>(features, W, mu, n_norm,
                                           ovfcnt, ovfrec, out);
    } else if (d_ws != nullptr && ws_size >= f16_bytes) {
        _Float16* f16t = (_Float16*)d_ws;
        cvt_f16_kernel<<<NFEAT / 8 / 256, 256, 0, stream>>>(features, f16t);
        pconv_f16_kernel<<<1024, 256, 0, stream>>>(f16t, edge_vec, W, mu,
                                                   edge_src, edge_dst, n_norm, out);
    } else {
        pconv_mfma_kernel<<<1024, 256, 0, stream>>>(features, edge_vec, W, mu,
                                                    edge_src, edge_dst, n_norm, out);
    }
}

// Round 19
// 216.550 us; speedup vs baseline: 1.1128x; 1.1128x over previous
//
#include <hip/hip_runtime.h>
#include <cmath>

// Problem constants (from reference)
#define NB 4
#define NP 8192            // 2^13 points per batch
#define NE 262144          // 2^18 edges per batch
#define NCIN 32
#define NCOUT 32
#define NH 16
#define GAMMA 4.0f
#define NFEAT (NB * NP * NCIN)      // 1,048,576 floats (4 MB)
#define TILES_PER_BATCH (NE / 64)

// Src-binning geometry (R11/R15/R17-proven best: 217 us total)
#define NSLAB 512                   // bin blocks; slab = 2048 contiguous edges
#define SLAB  2048
#define SREG  8                     // src regions per batch (1024 points each)
#define RPTS  1024                  // points per src region (64 KB f16 in LDS)
#define CAP   384                   // records per (slab, region); mean 256, +8 sigma
#define OVCAP 8192                  // overflow list capacity

typedef _Float16 half8 __attribute__((ext_vector_type(8)));
typedef float floatx4 __attribute__((ext_vector_type(4)));

// ---------------------------------------------------------------------------
// Bin pass (R17): records buffered in LDS, segments flushed contiguously
// (full-line coalesced stores; no partial-line RMW appends).
// ---------------------------------------------------------------------------
__global__ __launch_bounds__(256)
void bin_kernel(const float* __restrict__ edge_vec,
                const int* __restrict__ edge_src,
                const int* __restrict__ edge_dst,
                uint2* __restrict__ rec,
                int* __restrict__ scnt,
                int* __restrict__ ovfcnt,
                uint4* __restrict__ ovfrec)
{
    __shared__ uint2 buf[SREG][CAP];                    // 24 KiB record buffer
    __shared__ int lcnt[SREG];
    const int tid = threadIdx.x;
    if (tid < SREG) lcnt[tid] = 0;
    __syncthreads();

    const long e0 = (long)blockIdx.x * SLAB;
    const int batch = (int)(e0 >> 18);
    const long segbase = (long)blockIdx.x * SREG;

    #pragma unroll 1
    for (int k = 0; k < SLAB / 256; ++k) {
        const long e = e0 + k * 256 + tid;              // coalesced
        const float* ev = edge_vec + e * 3;
        const float vx = ev[0], vy = ev[1], vz = ev[2];
        // self-interaction zeroing in ref is a numeric no-op (r<1e-10 -> r=0)
        const float r = sqrtf(vx * vx + vy * vy + vz * vz);
        const int src = edge_src[e];
        const int dst = edge_dst[e];
        const int rg  = src >> 10;                      // src region 0..7
        const int pos = atomicAdd(&lcnt[rg], 1);        // LDS atomic
        if (pos < CAP) {
            uint2 rc;
            rc.x = __float_as_uint(r);
            rc.y = (unsigned)(src & 1023) | ((unsigned)dst << 10);
            buf[rg][pos] = rc;                          // LDS write, no fabric
        } else {
            const int op = atomicAdd(ovfcnt, 1);        // ~never taken
            if (op < OVCAP) {
                uint4 rc;
                rc.x = __float_as_uint(r);
                rc.y = (unsigned)src;
                rc.z = (unsigned)dst;
                rc.w = (unsigned)batch;
                ovfrec[op] = rc;
            }
        }
    }
    __syncthreads();

    #pragma unroll 1
    for (int rg = 0; rg < SREG; ++rg) {
        const int c = min(lcnt[rg], CAP);
        uint2* dstp = rec + (segbase + rg) * CAP;
        for (int i = tid; i < c; i += 256)
            dstp[i] = buf[rg][i];
    }
    if (tid < SREG) scnt[segbase + tid] = min(lcnt[tid], CAP);
}

// ---------------------------------------------------------------------------
// Main kernel (R15/R17 verbatim — best measured: ~135 us, FETCH 21 MB).
// R11 geometry: 96 KB LDS (wsw + flds) + 24 KB record staging,
// 256 blocks x 512 thr, 1 block/CU.
//
// Measured invariant (R13/R14/R15/R17): duration = atomic segments x 64 B
// / ~1.0 TB/s — the device-scope atomic RMW machinery's retirement rate is
// the floor. All alternatives tested and falsified: occupancy x2 (R13),
// record prefetch (R14), zero in-loop global loads (R15), 4x fewer atomic
// bytes via LDS combine (R16, lost more to serialization), 4-chain MFMA
// ILP (R18). This configuration is the empirical optimum.
//
// GEMM view: msg[e, o] = sum_k Z[e,k] * W2T[k,o],  k = h*32 + i, K = 512
//   Z[e, h*32+i] = rbf_h(e) * x_src[e][i]
// MFMA f32_16x16x32_f16 layouts (HW-verified, learn_hip m89/m91):
//   A: lane holds A[m=lane&15][k_local=(lane>>4)*8+j], j=0..7
//   B: lane holds B[k_local][n=lane&15]
//   D: lane holds D[row=(lane>>4)*4+rr][col=m]
// Masked tail rows: r=1e9 -> rbf=0 -> D-row=0 -> atomicAdd of 0 (harmless).
// ---------------------------------------------------------------------------
__global__ __launch_bounds__(512, 2)
void pconv_src_kernel(const float* __restrict__ features,
                      const float* __restrict__ W,
                      const float* __restrict__ mu,
                      const int* __restrict__ n_norm_p,
                      const uint2* __restrict__ rec,
                      const int* __restrict__ scnt,
                      float* __restrict__ out)
{
    __shared__ _Float16 wsw[16 * 2 * 64 * 8];      // 32 KiB, B-fragment order
    __shared__ _Float16 flds[RPTS * NCIN];         // 64 KiB region features
    __shared__ uint2    recs[8][CAP];              // 24 KiB per-wave records
    __shared__ float mus[16];

    const int tid = threadIdx.x;                   // 0..511
    for (int idx = tid; idx < 16384; idx += 512) {
        int j = idx & 7;
        int l = (idx >> 3) & 63;
        int u = (idx >> 9) & 1;
        int s = idx >> 10;
        int n = (l & 15) + (u << 4);               // output channel o
        int i = ((l >> 4) << 3) | j;               // input channel
        wsw[idx] = (_Float16)W[(s * NCOUT + n) * NCIN + i];
    }
    if (tid < 16) mus[tid] = mu[tid];

    const int bin   = blockIdx.x >> 3;             // 0..31 = batch*8 + region
    const int sub   = blockIdx.x & 7;
    const int batch = bin >> 3;
    const int reg   = bin & 7;

    // stage this region's features: f32 global -> f16 LDS (128 KB read)
    const float* fb = features + ((long)batch * NP + (long)reg * RPTS) * NCIN;
    for (int j = tid; j < RPTS * NCIN / 8; j += 512) {
        const floatx4* s = (const floatx4*)fb + (long)j * 2;
        floatx4 v0 = s[0], v1 = s[1];
        half8 h;
        h[0] = (_Float16)v0[0]; h[1] = (_Float16)v0[1];
        h[2] = (_Float16)v0[2]; h[3] = (_Float16)v0[3];
        h[4] = (_Float16)v1[0]; h[5] = (_Float16)v1[1];
        h[6] = (_Float16)v1[2]; h[7] = (_Float16)v1[3];
        *((half8*)flds + j) = h;
    }
    __syncthreads();

    const int lane = tid & 63;
    const int wv   = tid >> 6;                     // 0..7
    const int m    = lane & 15;                    // edge row / channel col
    const int q    = lane >> 4;

    const int nn = n_norm_p[0];
    const float scale = (nn > 0) ? rsqrtf((float)nn) : 1.0f;
    float* obase = out + ((long)batch * NP) * NCOUT;

    #pragma unroll 1
    for (int sl = 0; sl < 2; ++sl) {
        // this wave's slab: 16 slabs per sub, 2 per wave
        const int slab = batch * 128 + sub * 16 + wv * 2 + sl;
        const long segi = (long)slab * SREG + reg;
        const int cnt = scnt[segi];
        const uint2* rb = rec + segi * CAP;
        if (cnt <= 0) continue;

        // ---- stage the whole segment into this wave's LDS area
        for (int i = lane; i < cnt; i += 64)
            recs[wv][i] = rb[i];

        #pragma unroll 1
        for (int c0 = 0; c0 < cnt; c0 += 16) {
            const bool act = (c0 + m) < cnt;
            const uint2 rc = recs[wv][act ? (c0 + m) : 0];   // LDS read
            const float r  = act ? __uint_as_float(rc.x) : 1e9f;
            const int  sL  = (int)(rc.y & 1023u);

            // gather from LDS: one ds_read_b128 per lane, no fabric traffic
            half8 xh = *(const half8*)(flds + sL * NCIN + q * 8);

            float rbf[16];
            #pragma unroll
            for (int s = 0; s < 16; ++s) {
                float d = r - mus[s];
                rbf[s] = __expf(-GAMMA * d * d);   // masked -> 0
            }

            floatx4 accLo = {0.f, 0.f, 0.f, 0.f};  // channels 0..15
            floatx4 accHi = {0.f, 0.f, 0.f, 0.f};  // channels 16..31

            #pragma unroll
            for (int s = 0; s < 16; ++s) {
                const _Float16 rh = (_Float16)rbf[s];
                half8 a = xh * rh;                 // 4x v_pk_mul_f16
                half8 b0 = *(const half8*)(wsw + ((s * 2 + 0) * 64 + lane) * 8);
                half8 b1 = *(const half8*)(wsw + ((s * 2 + 1) * 64 + lane) * 8);
                accLo = __builtin_amdgcn_mfma_f32_16x16x32_f16(a, b0, accLo, 0, 0, 0);
                accHi = __builtin_amdgcn_mfma_f32_16x16x32_f16(a, b1, accHi, 0, 0, 0);
            }

            // Epilogue: D[row=q*4+rr][col=m]; 16 lanes cover 16 consecutive
            // channels -> coalesced 64 B atomic segments, fire-and-forget.
            #pragma unroll
            for (int rr = 0; rr < 4; ++rr) {
                const unsigned y2 = (unsigned)__shfl((int)rc.y, (q << 2) + rr, 64);
                const int dst = (int)((y2 >> 10) & 8191u);
                float* orow = obase + (long)dst * NCOUT;
                atomicAdd(orow + m,      accLo[rr] * scale);
                atomicAdd(orow + m + 16, accHi[rr] * scale);
            }
        }
    }
}

// ---------------------------------------------------------------------------
// Overflow cleanup: scalar per-edge compute for CAP-spilled records
// (expected count: 0). f32 math, atomic scatter.
// ---------------------------------------------------------------------------
__global__ __launch_bounds__(256)
void ovf_kernel(const float* __restrict__ features,
                const float* __restrict__ W,
                const float* __restrict__ mu,
                const int* __restrict__ n_norm_p,
                const int* __restrict__ ovfcnt,
                const uint4* __restrict__ ovfrec,
                float* __restrict__ out)
{
    const int n = min(ovfcnt[0], OVCAP);
    if (n == 0) return;
    const int nn = n_norm_p[0];
    const float scale = (nn > 0) ? rsqrtf((float)nn) : 1.0f;

    for (int idx = blockIdx.x * blockDim.x + threadIdx.x; idx < n * NCOUT;
         idx += gridDim.x * blockDim.x) {
        const int e = idx >> 5, o = idx & 31;
        const uint4 rc = ovfrec[e];
        const float r = __uint_as_float(rc.x);
        const int src = (int)rc.y, dst = (int)rc.z, b = (int)rc.w;
        const float* x = features + ((long)b * NP + src) * NCIN;
        float acc = 0.f;
        for (int h = 0; h < NH; ++h) {
            float d = r - mu[h];
            float rb = __expf(-GAMMA * d * d);
            float s = 0.f;
            for (int i = 0; i < NCIN; ++i)
                s += W[(h * NCOUT + o) * NCIN + i] * x[i];
            acc += rb * s;
        }
        atomicAdd(out + ((long)b * NP + dst) * NCOUT + o, acc * scale);
    }
}

// ---------------------------------------------------------------------------
// Fallback A (ws >= 2 MB): round-5 pipeline verbatim (248 us).
// ---------------------------------------------------------------------------
__global__ __launch_bounds__(256)
void cvt_f16_kernel(const float* __restrict__ features, _Float16* __restrict__ f16t)
{
    const int i = blockIdx.x * blockDim.x + threadIdx.x;    // 0 .. 131071
    const floatx4* src = (const floatx4*)features + (long)i * 2;
    floatx4 v0 = src[0], v1 = src[1];
    half8 h;
    h[0] = (_Float16)v0[0]; h[1] = (_Float16)v0[1];
    h[2] = (_Float16)v0[2]; h[3] = (_Float16)v0[3];
    h[4] = (_Float16)v1[0]; h[5] = (_Float16)v1[1];
    h[6] = (_Float16)v1[2]; h[7] = (_Float16)v1[3];
    *((half8*)f16t + i) = h;
}

__global__ __launch_bounds__(256, 4)
void pconv_f16_kernel(const _Float16* __restrict__ feat16,
                      const float* __restrict__ edge_vec,
                      const float* __restrict__ W,
                      const float* __restrict__ mu,
                      const int* __restrict__ edge_src,
                      const int* __restrict__ edge_dst,
                      const int* __restrict__ n_norm_p,
                      float* __restrict__ out)
{
    __shared__ _Float16 wsw[16 * 2 * 64 * 8];
    __shared__ float mus[16];

    const int tid = threadIdx.x;
    for (int idx = tid; idx < 16384; idx += 256) {
        int j = idx & 7;
        int l = (idx >> 3) & 63;
        int u = (idx >> 9) & 1;
        int s = idx >> 10;
        int n = (l & 15) + (u << 4);
        int i = ((l >> 4) << 3) | j;
        wsw[idx] = (_Float16)W[(s * NCOUT + n) * NCIN + i];
    }
    if (tid < 16) mus[tid] = mu[tid];
    __syncthreads();

    const int lane = tid & 63;
    const int wv   = tid >> 6;
    const int m    = lane & 15;
    const int q    = lane >> 4;

    const int nn = n_norm_p[0];
    const float scale = (nn > 0) ? rsqrtf((float)nn) : 1.0f;

    const int g    = blockIdx.x & 7;
    const int bb   = g >> 1;
    const int sub  = g & 1;
    const int bi   = blockIdx.x >> 3;

    const _Float16* fbase = feat16 + ((long)bb << 13) * NCIN;
    float* obase = out + ((long)bb << 13) * NCOUT;
    const long ebatch = (long)bb * NE;

    for (int i = bi; i < TILES_PER_BATCH / 2; i += 128) {
        const int  tloc  = (i << 1) + sub;
        const long ebase = ebatch + (long)tloc * 64 + (long)wv * 16;
        const long ge    = ebase + m;
        const int  src   = __builtin_nontemporal_load(edge_src + ge);

        half8 xh = *(const half8*)(fbase + (long)src * NCIN + q * 8);

        const float* ev = edge_vec + ge * 3;
        float vx = __builtin_nontemporal_load(ev + 0);
        float vy = __builtin_nontemporal_load(ev + 1);
        float vz = __builtin_nontemporal_load(ev + 2);
        float r = sqrtf(vx * vx + vy * vy + vz * vz);

        float rbf[16];
        #pragma unroll
        for (int s = 0; s < 16; ++s) {
            float d = r - mus[s];
            rbf[s] = __expf(-GAMMA * d * d);
        }

        floatx4 accLo = {0.f, 0.f, 0.f, 0.f};
        floatx4 accHi = {0.f, 0.f, 0.f, 0.f};

        #pragma unroll
        for (int s = 0; s < 16; ++s) {
            const _Float16 rh = (_Float16)rbf[s];
            half8 a = xh * rh;
            half8 b0 = *(const half8*)(wsw + ((s * 2 + 0) * 64 + lane) * 8);
            half8 b1 = *(const half8*)(wsw + ((s * 2 + 1) * 64 + lane) * 8);
            accLo = __builtin_amdgcn_mfma_f32_16x16x32_f16(a, b0, accLo, 0, 0, 0);
            accHi = __builtin_amdgcn_mfma_f32_16x16x32_f16(a, b1, accHi, 0, 0, 0);
        }

        #pragma unroll
        for (int rr = 0; rr < 4; ++rr) {
            const long e2  = ebase + q * 4 + rr;
            const int  dst = __builtin_nontemporal_load(edge_dst + e2);
            float* orow = obase + (long)dst * NCOUT;
            atomicAdd(orow + m,      accLo[rr] * scale);
            atomicAdd(orow + m + 16, accHi[rr] * scale);
        }
    }
}

// ---------------------------------------------------------------------------
// Fallback B (no workspace): round-3 kernel (f32 gathers).
// ---------------------------------------------------------------------------
__global__ __launch_bounds__(256, 4)
void pconv_mfma_kernel(const float* __restrict__ features,
                       const float* __restrict__ edge_vec,
                       const float* __restrict__ W,
                       const float* __restrict__ mu,
                       const int* __restrict__ edge_src,
                       const int* __restrict__ edge_dst,
                       const int* __restrict__ n_norm_p,
                       float* __restrict__ out)
{
    __shared__ _Float16 wsw[16 * 2 * 64 * 8];
    __shared__ float mus[16];

    const int tid = threadIdx.x;
    for (int idx = tid; idx < 16384; idx += 256) {
        int j = idx & 7;
        int l = (idx >> 3) & 63;
        int u = (idx >> 9) & 1;
        int s = idx >> 10;
        int n = (l & 15) + (u << 4);
        int i = ((l >> 4) << 3) | j;
        wsw[idx] = (_Float16)W[(s * NCOUT + n) * NCIN + i];
    }
    if (tid < 16) mus[tid] = mu[tid];
    __syncthreads();

    const int lane = tid & 63;
    const int wv   = tid >> 6;
    const int m    = lane & 15;
    const int q    = lane >> 4;

    const int nn = n_norm_p[0];
    const float scale = (nn > 0) ? rsqrtf((float)nn) : 1.0f;

    const int g    = blockIdx.x & 7;
    const int bb   = g >> 1;
    const int sub  = g & 1;
    const int bi   = blockIdx.x >> 3;

    const float* fbase = features + ((long)bb << 13) * NCIN;
    float* obase = out + ((long)bb << 13) * NCOUT;
    const long ebatch = (long)bb * NE;

    for (int i = bi; i < TILES_PER_BATCH / 2; i += 128) {
        const int  tloc  = (i << 1) + sub;
        const long ebase = ebatch + (long)tloc * 64 + (long)wv * 16;
        const long ge    = ebase + m;
        const int  src   = edge_src[ge];

        const float* xrow = fbase + (long)src * NCIN + q * 8;
        floatx4 xa = *(const floatx4*)(xrow);
        floatx4 xb = *(const floatx4*)(xrow + 4);

        const float* ev = edge_vec + ge * 3;
        float vx = ev[0], vy = ev[1], vz = ev[2];
        float r = sqrtf(vx * vx + vy * vy + vz * vz);

        float rbf[16];
        #pragma unroll
        for (int s = 0; s < 16; ++s) {
            float d = r - mus[s];
            rbf[s] = __expf(-GAMMA * d * d);
        }

        floatx4 accLo = {0.f, 0.f, 0.f, 0.f};
        floatx4 accHi = {0.f, 0.f, 0.f, 0.f};

        #pragma unroll
        for (int s = 0; s < 16; ++s) {
            const float rb = rbf[s];
            half8 a;
            a[0] = (_Float16)(rb * xa[0]);
            a[1] = (_Float16)(rb * xa[1]);
            a[2] = (_Float16)(rb * xa[2]);
            a[3] = (_Float16)(rb * xa[3]);
            a[4] = (_Float16)(rb * xb[0]);
            a[5] = (_Float16)(rb * xb[1]);
            a[6] = (_Float16)(rb * xb[2]);
            a[7] = (_Float16)(rb * xb[3]);
            half8 b0 = *(const half8*)(wsw + ((s * 2 + 0) * 64 + lane) * 8);
            half8 b1 = *(const half8*)(wsw + ((s * 2 + 1) * 64 + lane) * 8);
            accLo = __builtin_amdgcn_mfma_f32_16x16x32_f16(a, b0, accLo, 0, 0, 0);
            accHi = __builtin_amdgcn_mfma_f32_16x16x32_f16(a, b1, accHi, 0, 0, 0);
        }

        #pragma unroll
        for (int rr = 0; rr < 4; ++rr) {
            const long e2  = ebase + q * 4 + rr;
            const int  dst = edge_dst[e2];
            float* orow = obase + (long)dst * NCOUT;
            atomicAdd(orow + m,      accLo[rr] * scale);
            atomicAdd(orow + m + 16, accHi[rr] * scale);
        }
    }
}

extern "C" void kernel_launch(void* const* d_in, const int* in_sizes, int n_in,
                              void* d_out, int out_size, void* d_ws, size_t ws_size,
                              hipStream_t stream) {
    const float* features = (const float*)d_in[0];
    const float* edge_vec = (const float*)d_in[1];
    const float* W        = (const float*)d_in[2];
    const float* mu       = (const float*)d_in[3];
    const int*   edge_src = (const int*)d_in[4];
    const int*   edge_dst = (const int*)d_in[5];
    const int*   n_norm   = (const int*)d_in[6];
    float* out = (float*)d_out;

    // harness poisons d_out; all paths accumulate via atomics
    hipMemsetAsync(out, 0, (size_t)out_size * sizeof(float), stream);

    // ws layout: rec[512*8*CAP] (8 B) | scnt[4096] | ovfcnt | ovfrec[8192*16B]
    const size_t rec_bytes = (size_t)NSLAB * SREG * CAP * sizeof(uint2); // 12.6 MB
    const size_t cnt_bytes = (size_t)NSLAB * SREG * sizeof(int);         // 16 KB
    const size_t ovc_bytes = 64;
    const size_t ovr_bytes = (size_t)OVCAP * sizeof(uint4);              // 128 KB
    const size_t need_full = rec_bytes + cnt_bytes + ovc_bytes + ovr_bytes;
    const size_t f16_bytes = (size_t)NFEAT * sizeof(_Float16);           // 2 MB

    if (d_ws != nullptr && ws_size >= need_full) {
        char* ws = (char*)d_ws;
        uint2* rec    = (uint2*)ws;
        int*   scnt   = (int*)(ws + rec_bytes);
        int*   ovfcnt = (int*)(ws + rec_bytes + cnt_bytes);
        uint4* ovfrec = (uint4*)(ws + rec_bytes + cnt_bytes + ovc_bytes);

        hipMemsetAsync(ovfcnt, 0, sizeof(int), stream);
        bin_kernel<<<NSLAB, 256, 0, stream>>>(edge_vec, edge_src, edge_dst,
                                              rec, scnt, ovfcnt, ovfrec);
        // grid 256 = NB * SREG * 8 = 4*8*8 -> exactly 1 block/CU
        pconv_src_kernel<<<NB * SREG * 8, 512, 0, stream>>>(
            features, W, mu, n_norm, rec, scnt, out);
        ovf_kernel<<<64, 256, 0, stream>>>(features, W, mu, n_norm,
                                           ovfcnt, ovfrec, out);
    } else if (d_ws != nullptr && ws_size >= f16_bytes) {
        _Float16* f16t = (_Float16*)d_ws;
        cvt_f16_kernel<<<NFEAT / 8 / 256, 256, 0, stream>>>(features, f16t);
        pconv_f16_kernel<<<1024, 256, 0, stream>>>(f16t, edge_vec, W, mu,
                                                   edge_src, edge_dst, n_norm, out);
    } else {
        pconv_mfma_kernel<<<1024, 256, 0, stream>>>(features, edge_vec, W, mu,
                                                    edge_src, edge_dst, n_norm, out);
    }
}